// Round 1
// baseline (65493.561 us; speedup 1.0000x reference)
//
#include <hip/hip_runtime.h>
#include <hip/hip_bf16.h>

// AlphatRNN: B=128, T=512, D=256, H=1024, 2 layers, O=1 (fp32)
// Persistent-kernel design: 256 WGs x 512 thr, custom grid barrier.
// WG tile: 16 batch rows x 32 hidden cols, identical across all stages, so each
// thread owns ONE (b,h) element and carries h0/s0/h1/s1 in registers all 512 steps.
// Published K-spans (s0', h0, s1') move via agent-scope (sc1) atomics so the
// per-XCD L2s keep the weights cached (no acquire-side cache invalidation).

#define NB   128
#define TT   512
#define DD   256
#define HH   1024
#define NWG  256
#define NTHR 512
#define MT   16   // batch rows per WG   (P_b = 8)
#define NTL  32   // hidden cols per WG  (P_n = 32)

__device__ __forceinline__ float agent_load(const float* p) {
    return __hip_atomic_load(p, __ATOMIC_RELAXED, __HIP_MEMORY_SCOPE_AGENT);
}
__device__ __forceinline__ void agent_store(float* p, float v) {
    __hip_atomic_store(p, v, __ATOMIC_RELAXED, __HIP_MEMORY_SCOPE_AGENT);
}

// Grid barrier: fresh counter per instance (memset to 0 each launch).
// __syncthreads before arrive drains every wave's sc1 stores (vmcnt0 + s_barrier).
__device__ __forceinline__ void gbar(unsigned* ctr, int& barid)
{
    __syncthreads();
    if (threadIdx.x == 0) {
        unsigned* c = ctr + barid;
        __hip_atomic_fetch_add(c, 1u, __ATOMIC_RELEASE, __HIP_MEMORY_SCOPE_AGENT);
        while (__hip_atomic_load(c, __ATOMIC_RELAXED, __HIP_MEMORY_SCOPE_AGENT) != NWG)
            __builtin_amdgcn_s_sleep(1);
    }
    ++barid;
    __syncthreads();
}

// Stage a [MT][512] fp32 block of a published state span into LDS (coherent loads).
__device__ __forceinline__ void stage512_coh(float* dst, const float* src, int tid)
{
    #pragma unroll
    for (int i = 0; i < (MT * 512) / NTHR; ++i) {   // 16 iters, coalesced dwords
        int idx = tid + i * NTHR;
        int r = idx >> 9, c = idx & 511;
        dst[idx] = agent_load(src + (size_t)r * HH + c);
    }
}

// Accumulate acc[r] += S[r][kq-chunk] . W[n][kq-chunk].
// Thread (nl = tid&31, kq = tid>>5): weight row n0+nl, exclusive K-chunk -> no
// redundant L2 weight reads. LDS S reads are 2 addresses per wave (broadcast).
template<int SEGK>
__device__ __forceinline__ void accum(float acc[MT], const float* S, const float* wrow, int kq)
{
    constexpr int CH = SEGK / 16;   // 32 (state half) or 16 (x)
    const int kb = kq * CH;
    #pragma unroll
    for (int k4 = 0; k4 < CH; k4 += 4) {
        float4 w = *(const float4*)(wrow + kb + k4);
        #pragma unroll
        for (int r = 0; r < MT; ++r) {
            float4 s = *(const float4*)(S + r * SEGK + kb + k4);
            acc[r] = fmaf(s.x, w.x, fmaf(s.y, w.y, fmaf(s.z, w.z, fmaf(s.w, w.w, acc[r]))));
        }
    }
}

// Fold 16 K-chunk partials -> one value per owned (orow, ocol) element.
__device__ __forceinline__ float reduce_own(float acc[MT], float (*red)[MT][NTL], int tid)
{
    #pragma unroll
    for (int r = 0; r < MT; ++r) acc[r] += __shfl_xor(acc[r], 32);
    const int nl = tid & 31;
    if (!(tid & 32)) {
        const int k2 = tid >> 6;            // 8 wave-groups
        #pragma unroll
        for (int r = 0; r < MT; ++r) red[k2][r][nl] = acc[r];
    }
    __syncthreads();
    const int orow = tid >> 5, ocol = tid & 31;
    float u = 0.f;
    #pragma unroll
    for (int j = 0; j < 8; ++j) u += red[j][orow][ocol];
    return u;
}

extern "C" __global__ void __launch_bounds__(NTHR, 1)
alphat_kernel(const float* __restrict__ x,
              const float* __restrict__ Wax0, const float* __restrict__ Uas0, const float* __restrict__ ba0,
              const float* __restrict__ Wih0, const float* __restrict__ Whh0, const float* __restrict__ bh0,
              const float* __restrict__ Wax1, const float* __restrict__ Uas1, const float* __restrict__ ba1,
              const float* __restrict__ Wih1, const float* __restrict__ Whh1, const float* __restrict__ bh1,
              const float* __restrict__ fcW, const float* __restrict__ fcb,
              float* __restrict__ out,
              float* s0b, float* s1b, float* h0b, unsigned* ctr)
{
    __shared__ float sS[MT][512];        // 32 KiB state-span staging (K-half)
    __shared__ float sX[MT][DD];         // 16 KiB x_t staging
    __shared__ float red[8][MT][NTL];    // 16 KiB partial reduce

    const int tid  = threadIdx.x;
    const int wg   = blockIdx.x;
    const int m0   = (wg >> 5) * MT;     // batch-row base
    const int n0   = (wg & 31) * NTL;    // hidden-col base
    const int nl   = tid & 31;
    const int kq   = tid >> 5;           // 16 K-chunks
    const int rown = n0 + nl;            // this thread's weight row
    const int orow = tid >> 5;           // owned element coords
    const int ocol = tid & 31;
    const int gb   = m0 + orow;
    const int gn   = n0 + ocol;

    const float bias_a0 = ba0[gn], bias_h0 = bh0[gn];
    const float bias_a1 = ba1[gn], bias_h1 = bh1[gn];

    float h0l = 0.f, s0l = 0.f, h1l = 0.f, s1l = 0.f;   // register-resident state
    int barid = 0;

    for (int t = 0; t < TT; ++t) {
        const int cur = t & 1;
        float* s0cur = s0b + (size_t)cur       * (NB * HH);
        float* s0nxt = s0b + (size_t)(cur ^ 1) * (NB * HH);
        float* s1cur = s1b + (size_t)cur       * (NB * HH);
        float* s1nxt = s1b + (size_t)(cur ^ 1) * (NB * HH);

        // stage x_t rows once per step (read-only input, plain loads)
        #pragma unroll
        for (int i = 0; i < (MT * DD) / NTHR; ++i) {
            int idx = tid + i * NTHR;
            int r = idx >> 8, c = idx & 255;
            sX[r][c] = x[(size_t)(m0 + r) * (TT * DD) + (size_t)t * DD + c];
        }

        float acc[MT];

        // ---- stage A: alpha0 = sigmoid(x@Wax0^T + s0@Uas0^T + ba0); s0' = a*h0 + (1-a)*s0
        #pragma unroll
        for (int r = 0; r < MT; ++r) acc[r] = 0.f;
        for (int h = 0; h < 2; ++h) {
            stage512_coh(&sS[0][0], s0cur + (size_t)m0 * HH + h * 512, tid);
            __syncthreads();
            accum<512>(acc, &sS[0][0], Uas0 + (size_t)rown * HH + h * 512, kq);
            __syncthreads();
        }
        accum<256>(acc, &sX[0][0], Wax0 + (size_t)rown * DD, kq);
        {
            float u  = reduce_own(acc, red, tid) + bias_a0;
            float al = 1.f / (1.f + __expf(-u));
            float sn = al * h0l + (1.f - al) * s0l;
            s0l = sn;
            agent_store(s0nxt + (size_t)gb * HH + gn, sn);
        }
        gbar(ctr, barid);

        // ---- stage B: h0 = tanh(x@Wih0^T + s0'@Whh0^T + bh0)
        #pragma unroll
        for (int r = 0; r < MT; ++r) acc[r] = 0.f;
        for (int h = 0; h < 2; ++h) {
            stage512_coh(&sS[0][0], s0nxt + (size_t)m0 * HH + h * 512, tid);
            __syncthreads();
            accum<512>(acc, &sS[0][0], Whh0 + (size_t)rown * HH + h * 512, kq);
            __syncthreads();
        }
        accum<256>(acc, &sX[0][0], Wih0 + (size_t)rown * DD, kq);
        {
            float v  = reduce_own(acc, red, tid) + bias_h0;
            float hn = tanhf(v);
            h0l = hn;
            agent_store(h0b + (size_t)gb * HH + gn, hn);
        }
        gbar(ctr, barid);

        // ---- stage C: alpha1 = sigmoid(h0@Wax1^T + s1@Uas1^T + ba1); s1' = a*h1 + (1-a)*s1
        #pragma unroll
        for (int r = 0; r < MT; ++r) acc[r] = 0.f;
        for (int h = 0; h < 2; ++h) {
            stage512_coh(&sS[0][0], h0b + (size_t)m0 * HH + h * 512, tid);
            __syncthreads();
            accum<512>(acc, &sS[0][0], Wax1 + (size_t)rown * HH + h * 512, kq);
            __syncthreads();
        }
        for (int h = 0; h < 2; ++h) {
            stage512_coh(&sS[0][0], s1cur + (size_t)m0 * HH + h * 512, tid);
            __syncthreads();
            accum<512>(acc, &sS[0][0], Uas1 + (size_t)rown * HH + h * 512, kq);
            __syncthreads();
        }
        {
            float u  = reduce_own(acc, red, tid) + bias_a1;
            float al = 1.f / (1.f + __expf(-u));
            float sn = al * h1l + (1.f - al) * s1l;
            s1l = sn;
            agent_store(s1nxt + (size_t)gb * HH + gn, sn);
        }
        gbar(ctr, barid);

        // ---- stage D: h1 = tanh(h0@Wih1^T + s1'@Whh1^T + bh1)   (no publish needed)
        #pragma unroll
        for (int r = 0; r < MT; ++r) acc[r] = 0.f;
        for (int h = 0; h < 2; ++h) {
            stage512_coh(&sS[0][0], h0b + (size_t)m0 * HH + h * 512, tid);
            __syncthreads();
            accum<512>(acc, &sS[0][0], Wih1 + (size_t)rown * HH + h * 512, kq);
            __syncthreads();
        }
        for (int h = 0; h < 2; ++h) {
            stage512_coh(&sS[0][0], s1nxt + (size_t)m0 * HH + h * 512, tid);
            __syncthreads();
            accum<512>(acc, &sS[0][0], Whh1 + (size_t)rown * HH + h * 512, kq);
            __syncthreads();
        }
        {
            float v = reduce_own(acc, red, tid) + bias_h1;
            h1l = tanhf(v);
        }
        __syncthreads();   // protect sS/red before next step's staging
    }

    // ---- epilogue: all final state is register-resident; write outputs
    const size_t HIDB = NB;                 // hidden  [2][B][H] base
    const size_t SMOB = NB + 2 * NB * HH;   // smoothed[2][B][H] base
    const size_t o = (size_t)gb * HH + gn;
    out[HIDB + o]           = h0l;
    out[HIDB + NB * HH + o] = h1l;
    out[SMOB + o]           = s0l;
    out[SMOB + NB * HH + o] = s1l;

    // out[b] = sum_n h1[b,n]*fcW[n] + fcb  (reduce 32 owned cols per 32-lane group)
    float c = h1l * fcW[gn];
    #pragma unroll
    for (int off = 16; off; off >>= 1) c += __shfl_xor(c, off);
    if (nl == 0) {
        float addb = ((wg & 31) == 0) ? fcb[0] : 0.f;
        atomicAdd(out + gb, c + addb);
    }
}

extern "C" void kernel_launch(void* const* d_in, const int* in_sizes, int n_in,
                              void* d_out, int out_size, void* d_ws, size_t ws_size,
                              hipStream_t stream)
{
    const float* x    = (const float*)d_in[0];
    const float* Wax0 = (const float*)d_in[1];
    const float* Uas0 = (const float*)d_in[2];
    const float* ba0  = (const float*)d_in[3];
    const float* Wih0 = (const float*)d_in[4];
    const float* Whh0 = (const float*)d_in[5];
    const float* bh0  = (const float*)d_in[6];
    const float* Wax1 = (const float*)d_in[7];
    const float* Uas1 = (const float*)d_in[8];
    const float* ba1  = (const float*)d_in[9];
    const float* Wih1 = (const float*)d_in[10];
    const float* Whh1 = (const float*)d_in[11];
    const float* bh1  = (const float*)d_in[12];
    const float* fcW  = (const float*)d_in[13];
    const float* fcb  = (const float*)d_in[14];
    float* out = (float*)d_out;

    // ws layout: s0[2][B][H] | s1[2][B][H] | h0[B][H] | 2048 barrier counters
    float* s0b = (float*)d_ws;
    float* s1b = s0b + 2 * NB * HH;
    float* h0b = s1b + 2 * NB * HH;
    unsigned* ctr = (unsigned*)(h0b + NB * HH);
    const size_t ws_need = (size_t)(5 * NB * HH) * sizeof(float) + 2048 * sizeof(unsigned);

    hipMemsetAsync(d_ws, 0, ws_need, stream);
    hipMemsetAsync(d_out, 0, (size_t)out_size * sizeof(float), stream);

    alphat_kernel<<<dim3(NWG), dim3(NTHR), 0, stream>>>(
        x, Wax0, Uas0, ba0, Wih0, Whh0, bh0,
        Wax1, Uas1, ba1, Wih1, Whh1, bh1, fcW, fcb,
        out, s0b, s1b, h0b, ctr);
}

// Round 3
// 20900.542 us; speedup vs baseline: 3.1336x; 3.1336x over previous
//
#include <hip/hip_runtime.h>

// AlphatRNN B=128,T=512,D=256,H=1024,L=2,O=1 — bf16 MFMA persistent kernel.
// 256 WGs x 512 thr (8 waves). WG tile 16(b) x 32(n); waves = 2 n-tiles x 4 K-quarters.
// State master fp32 in waves 0/1 regs; published spans are bf16 via agent-scope
// atomics (coherent at L3; per-XCD L2 keeps weights hot). Grid swizzled so each
// XCD's 32 WGs share one 1.6MB bf16 weight slice -> L2-resident all 512 steps.
// R2 fix: stage_span row stride (256 u64/row, was 128) + builtin MFMA (hazards
// handled by compiler instead of hand s_nop).

typedef unsigned short u16;
typedef unsigned long long u64;
typedef __attribute__((ext_vector_type(8))) short short8;
typedef __attribute__((ext_vector_type(4))) float f32x4;

#define NB   128
#define TT   512
#define DD   256
#define HH   1024
#define NWG  256
#define NTHR 512
#define SPAN (NB * HH)          // elems of one published state span

// ---- ws layout (bytes) ----
#define S0_OFF  0u              // bf16 [2][128][1024]
#define S1_OFF  524288u         // bf16 [2][128][1024]
#define H0_OFF  1048576u        // bf16 [128][1024]
#define CTR_OFF 1310720u        // 2048 x u32 barrier counters
#define W_OFF   1318912u        // bf16 weights: 6x[1024][1024], then [1024][256]x2
#define NBIG    6291456u        // 6 * 1048576

__device__ __forceinline__ u16 f2bf(float f) {   // RNE, finite inputs only
    unsigned u = __builtin_bit_cast(unsigned, f);
    return (u16)((u + 0x7fffu + ((u >> 16) & 1u)) >> 16);
}

__device__ __forceinline__ u64 agent_load64(const u64* p) {
    return __hip_atomic_load(p, __ATOMIC_RELAXED, __HIP_MEMORY_SCOPE_AGENT);
}
__device__ __forceinline__ void agent_store16(u16* p, u16 v) {
    __hip_atomic_store(p, v, __ATOMIC_RELAXED, __HIP_MEMORY_SCOPE_AGENT);
}

// grid barrier: fresh counter per instance (memset each launch/replay)
__device__ __forceinline__ void gbar(unsigned* ctr, int& barid)
{
    __syncthreads();
    if (threadIdx.x == 0) {
        unsigned* c = ctr + barid;
        __hip_atomic_fetch_add(c, 1u, __ATOMIC_RELEASE, __HIP_MEMORY_SCOPE_AGENT);
        while (__hip_atomic_load(c, __ATOMIC_RELAXED, __HIP_MEMORY_SCOPE_AGENT) != NWG)
            __builtin_amdgcn_s_sleep(1);
    }
    ++barid;
    __syncthreads();
}

// stage one 16-row bf16 span slice [16][1024] into LDS (stride 2048B, XOR-swizzled)
// row = 1024 bf16 = 2048 B = 256 u64 chunks  ->  global row stride is <<8 u64.
__device__ __forceinline__ void stage_span(char* dst, const u16* src, int m0, int tid)
{
    const u64* s64 = (const u64*)src;
    #pragma unroll
    for (int i = 0; i < 8; ++i) {
        int idx = tid + (i << 9);
        int row = idx >> 8, ch = idx & 255;              // 256 x 8B chunks per row
        u64 v = agent_load64(s64 + ((size_t)(m0 + row) << 8) + ch);
        *(u64*)(dst + row * 2048 + ((ch << 3) ^ ((row & 7) << 4))) = v;
    }
}

// stage x_t [16][256] fp32 -> bf16 LDS (stride 512B, swizzled). 512 thr x 8 elems.
__device__ __forceinline__ void stage_x(char* dst, const float* x, int m0, int t, int tid)
{
    int row = tid >> 5, e0 = (tid & 31) << 3;
    const float* p = x + (((size_t)(m0 + row) * TT + t) << 8) + e0;
    float4 a = *(const float4*)p;
    float4 b = *(const float4*)(p + 4);
    short8 v;
    v[0] = (short)f2bf(a.x); v[1] = (short)f2bf(a.y); v[2] = (short)f2bf(a.z); v[3] = (short)f2bf(a.w);
    v[4] = (short)f2bf(b.x); v[5] = (short)f2bf(b.y); v[6] = (short)f2bf(b.z); v[7] = (short)f2bf(b.w);
    *(short8*)(dst + row * 512 + ((e0 << 1) ^ ((row & 7) << 4)));
    *(short8*)(dst + row * 512 + ((e0 << 1) ^ ((row & 7) << 4))) = v;
}

// one K-span of S[16xK] @ W[n..n+16, K]^T via builtin mfma 16x16x32.
// A-frag and B-frag use the SAME (lane,elem)->k map (8 contiguous per lkg group),
// so any hardware k-permutation cancels between operands.
template<int NS>
__device__ __forceinline__ f32x4 mm(f32x4 acc, const char* A, int astride,
                                    const u16* W, int K, int wr, int ks0,
                                    int lrow, int lkg)
{
    const int rs = (lrow & 7) << 4;
    const char* ar = A + lrow * astride;
    const u16*  wp = W + (size_t)wr * K + ks0 * 32 + lkg * 8;
    #pragma unroll
    for (int s = 0; s < NS; ++s) {
        short8 a = *(const short8*)(ar + ((((ks0 + s) << 6) + (lkg << 4)) ^ rs));
        short8 b = *(const short8*)(wp + s * 32);
        acc = __builtin_amdgcn_mfma_f32_16x16x32_bf16(a, b, acc, 0, 0, 0);
    }
    return acc;
}

// fold 4 K-quarter partials into kq==0 waves
__device__ __forceinline__ f32x4 wgreduce(f32x4 acc, int nt, int kq, int lane,
                                          f32x4 (*red)[2][64])
{
    if (kq) red[kq - 1][nt][lane] = acc;
    __syncthreads();
    if (!kq) acc = acc + red[0][nt][lane] + red[1][nt][lane] + red[2][nt][lane];
    return acc;
}

__global__ void conv_weights(const float* Uas0, const float* Whh0, const float* Wax1,
                             const float* Uas1, const float* Wih1, const float* Whh1,
                             const float* Wax0, const float* Wih0, u16* dst)
{
    for (size_t i = (size_t)blockIdx.x * blockDim.x + threadIdx.x; i < 6815744u;
         i += (size_t)gridDim.x * blockDim.x) {
        const float* src; size_t off;
        if (i < NBIG) {
            int seg = (int)(i >> 20); off = i & 1048575u;
            src = seg == 0 ? Uas0 : seg == 1 ? Whh0 : seg == 2 ? Wax1
                : seg == 3 ? Uas1 : seg == 4 ? Wih1 : Whh1;
        } else {
            size_t j = i - NBIG; off = j & 262143u;
            src = (j >> 18) ? Wih0 : Wax0;
        }
        dst[i] = f2bf(src[off]);
    }
}

extern "C" __global__ void __launch_bounds__(NTHR, 1)
alphat_mfma(const float* __restrict__ x,
            const u16* __restrict__ wUas0, const u16* __restrict__ wWhh0,
            const u16* __restrict__ wWax1, const u16* __restrict__ wUas1,
            const u16* __restrict__ wWih1, const u16* __restrict__ wWhh1,
            const u16* __restrict__ wWax0, const u16* __restrict__ wWih0,
            const float* __restrict__ ba0, const float* __restrict__ bh0,
            const float* __restrict__ ba1, const float* __restrict__ bh1,
            const float* __restrict__ fcW, const float* __restrict__ fcb,
            float* __restrict__ out,
            u16* s0b, u16* s1b, u16* h0b, unsigned* ctr)
{
    __shared__ alignas(16) char sS[16 * 2048];   // 32 KB span buffer
    __shared__ alignas(16) char sX[16 * 512];    //  8 KB x_t buffer
    __shared__ f32x4 red[3][2][64];              //  6 KB reduce buffer

    const int tid  = threadIdx.x;
    const int wv   = tid >> 6;
    const int lane = tid & 63;
    const int nt   = wv & 1;          // n-tile 0/1
    const int kq   = wv >> 1;         // K-quarter 0..3
    const int lrow = lane & 15;
    const int lkg  = lane >> 4;

    // XCD swizzle: same-XCD WGs (bid%8) share the same 4 n-groups -> weights L2-hot
    const int wg = blockIdx.x;
    const int ng = (wg & 7) * 4 + ((wg >> 3) & 3);
    const int mg = wg >> 5;
    const int m0 = mg * 16;
    const int n0 = ng * 32;

    const int wr    = n0 + nt * 16 + lrow;   // B-frag weight row
    const int gcol  = n0 + nt * 16 + lrow;   // owned C col
    const int grow0 = m0 + lkg * 4;          // owned C rows base

    const float vba0 = ba0[gcol], vbh0 = bh0[gcol];
    const float vba1 = ba1[gcol], vbh1 = bh1[gcol];

    float h0l[4] = {0,0,0,0}, s0l[4] = {0,0,0,0};
    float h1l[4] = {0,0,0,0}, s1l[4] = {0,0,0,0};
    int barid = 0;

    for (int t = 0; t < TT; ++t) {
        const int cur = t & 1;
        u16* s0cur = s0b + cur * SPAN;  u16* s0nxt = s0b + (cur ^ 1) * SPAN;
        u16* s1cur = s1b + cur * SPAN;  u16* s1nxt = s1b + (cur ^ 1) * SPAN;

        // ---- A: alpha0 = sig(x@Wax0^T + s0@Uas0^T + ba0); s0' = a*h0+(1-a)*s0
        stage_x(sX, x, m0, t, tid);
        stage_span(sS, s0cur, m0, tid);
        __syncthreads();
        f32x4 acc = {0.f, 0.f, 0.f, 0.f};
        acc = mm<8>(acc, sS, 2048, wUas0, HH, wr, kq * 8, lrow, lkg);
        acc = mm<2>(acc, sX,  512, wWax0, DD, wr, kq * 2, lrow, lkg);
        acc = wgreduce(acc, nt, kq, lane, red);
        if (wv < 2) {
            #pragma unroll
            for (int r = 0; r < 4; ++r) {
                float u  = acc[r] + vba0;
                float al = 1.f / (1.f + __expf(-u));
                float sn = al * h0l[r] + (1.f - al) * s0l[r];
                s0l[r] = sn;
                agent_store16(s0nxt + (size_t)(grow0 + r) * HH + gcol, f2bf(sn));
            }
        }
        gbar(ctr, barid);

        // ---- B: h0 = tanh(x@Wih0^T + s0'@Whh0^T + bh0)
        stage_span(sS, s0nxt, m0, tid);
        __syncthreads();
        acc = f32x4{0.f, 0.f, 0.f, 0.f};
        acc = mm<8>(acc, sS, 2048, wWhh0, HH, wr, kq * 8, lrow, lkg);
        acc = mm<2>(acc, sX,  512, wWih0, DD, wr, kq * 2, lrow, lkg);
        acc = wgreduce(acc, nt, kq, lane, red);
        if (wv < 2) {
            #pragma unroll
            for (int r = 0; r < 4; ++r) {
                float hn = tanhf(acc[r] + vbh0);
                h0l[r] = hn;
                agent_store16(h0b + (size_t)(grow0 + r) * HH + gcol, f2bf(hn));
            }
        }
        gbar(ctr, barid);

        // ---- C: alpha1 = sig(h0@Wax1^T + s1@Uas1^T + ba1); s1' = a*h1+(1-a)*s1
        stage_span(sS, h0b, m0, tid);
        __syncthreads();
        acc = f32x4{0.f, 0.f, 0.f, 0.f};
        acc = mm<8>(acc, sS, 2048, wWax1, HH, wr, kq * 8, lrow, lkg);
        __syncthreads();                       // all reads of sS(h0) done
        stage_span(sS, s1cur, m0, tid);
        __syncthreads();
        acc = mm<8>(acc, sS, 2048, wUas1, HH, wr, kq * 8, lrow, lkg);
        acc = wgreduce(acc, nt, kq, lane, red);
        if (wv < 2) {
            #pragma unroll
            for (int r = 0; r < 4; ++r) {
                float u  = acc[r] + vba1;
                float al = 1.f / (1.f + __expf(-u));
                float sn = al * h1l[r] + (1.f - al) * s1l[r];
                s1l[r] = sn;
                agent_store16(s1nxt + (size_t)(grow0 + r) * HH + gcol, f2bf(sn));
            }
        }
        gbar(ctr, barid);

        // ---- D: h1 = tanh(h0@Wih1^T + s1'@Whh1^T + bh1)   (register-only result)
        stage_span(sS, h0b, m0, tid);
        __syncthreads();
        acc = f32x4{0.f, 0.f, 0.f, 0.f};
        acc = mm<8>(acc, sS, 2048, wWih1, HH, wr, kq * 8, lrow, lkg);
        __syncthreads();
        stage_span(sS, s1nxt, m0, tid);
        __syncthreads();
        acc = mm<8>(acc, sS, 2048, wWhh1, HH, wr, kq * 8, lrow, lkg);
        acc = wgreduce(acc, nt, kq, lane, red);
        if (wv < 2) {
            #pragma unroll
            for (int r = 0; r < 4; ++r) h1l[r] = tanhf(acc[r] + vbh1);
        }
        // next iteration's staging is fenced by wgreduce's __syncthreads
    }

    // ---- epilogue ----
    if (wv < 2) {
        const size_t HIDB = NB, SMOB = NB + 2 * (size_t)SPAN;
        #pragma unroll
        for (int r = 0; r < 4; ++r) {
            size_t o = (size_t)(grow0 + r) * HH + gcol;
            out[HIDB + o]        = h0l[r];
            out[HIDB + SPAN + o] = h1l[r];
            out[SMOB + o]        = s0l[r];
            out[SMOB + SPAN + o] = s1l[r];
        }
        // out[b] = sum_n h1[b,n]*fcW[n] + fcb
        #pragma unroll
        for (int r = 0; r < 4; ++r) {
            float v = h1l[r] * fcW[gcol];
            v += __shfl_xor(v, 1); v += __shfl_xor(v, 2);
            v += __shfl_xor(v, 4); v += __shfl_xor(v, 8);
            if (lrow == 0) {
                if (ng == 0 && nt == 0) v += fcb[0];
                atomicAdd(out + grow0 + r, v);
            }
        }
    }
}

extern "C" void kernel_launch(void* const* d_in, const int* in_sizes, int n_in,
                              void* d_out, int out_size, void* d_ws, size_t ws_size,
                              hipStream_t stream)
{
    const float* x    = (const float*)d_in[0];
    const float* Wax0 = (const float*)d_in[1];
    const float* Uas0 = (const float*)d_in[2];
    const float* ba0  = (const float*)d_in[3];
    const float* Wih0 = (const float*)d_in[4];
    const float* Whh0 = (const float*)d_in[5];
    const float* bh0  = (const float*)d_in[6];
    const float* Wax1 = (const float*)d_in[7];
    const float* Uas1 = (const float*)d_in[8];
    const float* ba1  = (const float*)d_in[9];
    const float* Wih1 = (const float*)d_in[10];
    const float* Whh1 = (const float*)d_in[11];
    const float* bh1  = (const float*)d_in[12];
    const float* fcW  = (const float*)d_in[13];
    const float* fcb  = (const float*)d_in[14];
    float* out = (float*)d_out;

    char* ws = (char*)d_ws;
    u16* s0b = (u16*)(ws + S0_OFF);
    u16* s1b = (u16*)(ws + S1_OFF);
    u16* h0b = (u16*)(ws + H0_OFF);
    unsigned* ctr = (unsigned*)(ws + CTR_OFF);
    u16* wbase = (u16*)(ws + W_OFF);
    u16* wUas0 = wbase + 0 * 1048576;
    u16* wWhh0 = wbase + 1 * 1048576;
    u16* wWax1 = wbase + 2 * 1048576;
    u16* wUas1 = wbase + 3 * 1048576;
    u16* wWih1 = wbase + 4 * 1048576;
    u16* wWhh1 = wbase + 5 * 1048576;
    u16* wWax0 = wbase + 6 * 1048576;
    u16* wWih0 = wbase + 6 * 1048576 + 262144;

    // zero state spans + barrier counters + output (accumulated via atomics)
    hipMemsetAsync(d_ws, 0, CTR_OFF + 8192u, stream);
    hipMemsetAsync(d_out, 0, (size_t)out_size * sizeof(float), stream);

    conv_weights<<<dim3(1024), dim3(256), 0, stream>>>(
        Uas0, Whh0, Wax1, Uas1, Wih1, Whh1, Wax0, Wih0, wbase);

    alphat_mfma<<<dim3(NWG), dim3(NTHR), 0, stream>>>(
        x, wUas0, wWhh0, wWax1, wUas1, wWih1, wWhh1, wWax0, wWih0,
        ba0, bh0, ba1, bh1, fcW, fcb, out, s0b, s1b, h0b, ctr);
}